// Round 11
// baseline (1224.475 us; speedup 1.0000x reference)
//
#include <hip/hip_runtime.h>

#define DEV static __device__ __forceinline__

// ---------------------------------------------------------------- encoder ---

struct EncW {
  const float* cw[4]; const float* cb[4]; const float* g[4]; const float* bt[4];
  const float* rw[4]; const float* rb[4]; const float* rg[4]; const float* rbt[4];
};

// One GCN layer, f32 activations, in-place in a 64x220 LDS buffer.
// act layout: [c][t*22+v], stride 220. S = 4840-float scratch multiplexed
// through rw -> Tm -> A -> cw (disjoint phases): LDS < 80KB, 2 blocks/CU.
template<int CI, int CO>
DEV void gcn_layer32(int tid,
    const float* __restrict__ cw, const float* __restrict__ cb,
    const float* __restrict__ gg, const float* __restrict__ bt,
    const float* __restrict__ rw, const float* __restrict__ rb,
    const float* __restrict__ rg, const float* __restrict__ rbt,
    const float* __restrict__ TmL, const float* __restrict__ AL, float preL,
    float* __restrict__ act, float* __restrict__ S,
    float* __restrict__ rmul, float* __restrict__ radd,
    float* __restrict__ cmul, float* __restrict__ cadd)
{
  constexpr int COP8 = (CO + 7) & ~7;         // 8, 32, or 64
  constexpr int NT = (COP8 / 8) * 55;         // o-oct x p-quad tasks (<=440)
  const float inv = 0.99999499987f;           // 1/sqrt(1+1e-5)

  // ---- stage rw^T (padded) + BN consts ----
  for (int idx = tid; idx < CI * COP8; idx += 512) {
    int c = idx / COP8, o = idx % COP8;
    S[idx] = (o < CO) ? rw[o * CI + c] : 0.f;
  }
  for (int idx = tid; idx < 64; idx += 512) {
    bool ok = idx < CO;
    float rm = ok ? rg[idx] * inv : 0.f;
    float cm = ok ? gg[idx] * inv : 0.f;
    rmul[idx] = rm;
    radd[idx] = ok ? rb[idx] * rm + rbt[idx] : 0.f;
    cmul[idx] = cm;
    cadd[idx] = ok ? cb[idx] * cm + bt[idx] : 0.f;
  }
  __syncthreads();

  // ---- 2a: residual channel-mix -> registers (BN applied) ----
  float racc[32];
  int oo = tid / 55, pp = tid % 55;     // valid when tid < NT
  if (tid < NT) {
    #pragma unroll
    for (int k = 0; k < 32; ++k) racc[k] = 0.f;
    #pragma unroll 4
    for (int c = 0; c < CI; ++c) {
      const float* wr = S + c * COP8 + oo * 8;
      float4 w0 = *(const float4*)(wr);
      float4 w1 = *(const float4*)(wr + 4);
      float4 av = *(const float4*)(act + c * 220 + pp * 4);
      float wv[8] = {w0.x,w0.y,w0.z,w0.w,w1.x,w1.y,w1.z,w1.w};
      #pragma unroll
      for (int o = 0; o < 8; ++o) {
        racc[o*4+0] += wv[o]*av.x; racc[o*4+1] += wv[o]*av.y;
        racc[o*4+2] += wv[o]*av.z; racc[o*4+3] += wv[o]*av.w;
      }
    }
    #pragma unroll
    for (int o = 0; o < 8; ++o) {
      float m = rmul[oo * 8 + o], a = radd[oo * 8 + o];
      #pragma unroll
      for (int k = 0; k < 4; ++k) racc[o*4+k] = racc[o*4+k]*m + a;
    }
  }
  __syncthreads();

  // ---- stage TmT: S[(t*10+q)*22+v] = Tm[v*100+t*10+q] ----
  for (int idx = tid; idx < 2200; idx += 512) {
    int tq = idx / 22, v = idx % 22;
    int t = tq / 10, q = tq % 10;
    S[idx] = TmL[v * 100 + t * 10 + q];
  }
  __syncthreads();

  // ---- 2b: temporal mix, in place (v2-major) ----
  for (int idx = tid; idx < CI * 11; idx += 512) {
    int v2 = idx % 11, c = idx / 11;
    float* base = act + c * 220 + v2 * 2;
    float xin[10][2];
    #pragma unroll
    for (int t = 0; t < 10; ++t) { xin[t][0] = base[t*22]; xin[t][1] = base[t*22+1]; }
    float ya[10][2];
    #pragma unroll
    for (int q = 0; q < 10; ++q) { ya[q][0] = 0.f; ya[q][1] = 0.f; }
    #pragma unroll
    for (int t = 0; t < 10; ++t) {
      const float* tm = S + t * 220 + v2 * 2;
      #pragma unroll
      for (int q = 0; q < 10; ++q) {
        ya[q][0] += tm[q*22]   * xin[t][0];
        ya[q][1] += tm[q*22+1] * xin[t][1];
      }
    }
    #pragma unroll
    for (int q = 0; q < 10; ++q) { base[q*22] = ya[q][0]; base[q*22+1] = ya[q][1]; }
  }
  __syncthreads();

  // ---- stage A ----
  for (int idx = tid; idx < 4840; idx += 512) S[idx] = AL[idx];
  __syncthreads();

  // ---- 3: spatial mix, in place (t-major) ----
  for (int idx = tid; idx < CI * 10; idx += 512) {
    int t = idx % 10, c = idx / 10;
    float* row = act + c * 220 + t * 22;
    float yin[22];
    #pragma unroll
    for (int v = 0; v < 22; ++v) yin[v] = row[v];
    float za[22];
    #pragma unroll
    for (int w = 0; w < 22; ++w) za[w] = 0.f;
    #pragma unroll 2
    for (int v = 0; v < 22; ++v) {
      const float* ar = S + (t * 22 + v) * 22;
      float y0 = yin[v];
      #pragma unroll
      for (int w = 0; w < 22; ++w) za[w] += y0 * ar[w];
    }
    #pragma unroll
    for (int w = 0; w < 22; ++w) row[w] = za[w];
  }
  __syncthreads();

  // ---- stage cw^T ----
  for (int idx = tid; idx < CI * COP8; idx += 512) {
    int c = idx / COP8, o = idx % COP8;
    S[idx] = (o < CO) ? cw[o * CI + c] : 0.f;
  }
  __syncthreads();

  // ---- 4: main channel-mix into registers, barrier, in-place write ----
  float cacc[32];
  if (tid < NT) {
    #pragma unroll
    for (int k = 0; k < 32; ++k) cacc[k] = 0.f;
    #pragma unroll 4
    for (int c = 0; c < CI; ++c) {
      const float* wr = S + c * COP8 + oo * 8;
      float4 w0 = *(const float4*)(wr);
      float4 w1 = *(const float4*)(wr + 4);
      float4 av = *(const float4*)(act + c * 220 + pp * 4);
      float wv[8] = {w0.x,w0.y,w0.z,w0.w,w1.x,w1.y,w1.z,w1.w};
      #pragma unroll
      for (int o = 0; o < 8; ++o) {
        cacc[o*4+0] += wv[o]*av.x; cacc[o*4+1] += wv[o]*av.y;
        cacc[o*4+2] += wv[o]*av.z; cacc[o*4+3] += wv[o]*av.w;
      }
    }
  }
  __syncthreads();   // all reads of act complete before overwrite
  if (tid < NT) {
    #pragma unroll
    for (int o = 0; o < 8; ++o) {
      float m = cmul[oo * 8 + o], a = cadd[oo * 8 + o];
      #pragma unroll
      for (int k = 0; k < 4; ++k) {
        float y = cacc[o*4+k]*m + a + racc[o*4+k];
        act[(oo*8+o)*220 + pp*4 + k] = (y >= 0.f) ? y : preL * y;
      }
    }
  }
  __syncthreads();
}

__global__ __launch_bounds__(512, 4)
void enc_kernel(const float* __restrict__ x, const float* __restrict__ A,
                const float* __restrict__ Tm, const float* __restrict__ pre, EncW W,
                const float* __restrict__ qkvT, const float* __restrict__ qkv_b,
                float* __restrict__ h0_ws, float* __restrict__ k_ws,
                float* __restrict__ v_ws)
{
  __shared__ __align__(16) float act[64 * 220];   // 56320 B
  __shared__ __align__(16) float S[4840];         // 19360 B (rw/Tm/A/cw mux)
  __shared__ float rmul[64], radd[64], cmul[64], cadd[64];  // 1024 B

  const int tid = threadIdx.x;
  const int b = blockIdx.x;

  for (int idx = tid; idx < 660; idx += 512) {
    int c = idx / 220, r = idx % 220, t = r / 22, v = r % 22;
    act[c * 220 + t * 22 + v] = x[(((size_t)b * 10 + t) * 22 + v) * 3 + c];
  }
  float p0 = pre[0], p1 = pre[1], p2 = pre[2], p3 = pre[3];

  gcn_layer32<3, 64>(tid, W.cw[0], W.cb[0], W.g[0], W.bt[0], W.rw[0], W.rb[0], W.rg[0], W.rbt[0],
                     Tm, A, p0, act, S, rmul, radd, cmul, cadd);
  gcn_layer32<64, 32>(tid, W.cw[1], W.cb[1], W.g[1], W.bt[1], W.rw[1], W.rb[1], W.rg[1], W.rbt[1],
                     Tm + 2200, A + 4840, p1, act, S, rmul, radd, cmul, cadd);
  gcn_layer32<32, 64>(tid, W.cw[2], W.cb[2], W.g[2], W.bt[2], W.rw[2], W.rb[2], W.rg[2], W.rbt[2],
                     Tm + 4400, A + 9680, p2, act, S, rmul, radd, cmul, cadd);
  gcn_layer32<64, 3>(tid, W.cw[3], W.cb[3], W.g[3], W.bt[3], W.rw[3], W.rb[3], W.rg[3], W.rbt[3],
                     Tm + 6600, A + 14520, p3, act, S, rmul, radd, cmul, cadd);

  // build encD[t][d=v*3+c] in act rows 3..5; store h0
  float* encD = act + 3 * 220;
  for (int idx = tid; idx < 660; idx += 512) {
    int t = idx / 66, d = idx % 66, v = d / 3, c = d % 3;
    float val = act[c * 220 + t * 22 + v];
    encD[idx] = val;
    if (t == 9) h0_ws[(size_t)b * 66 + d] = val;
  }
  __syncthreads();

  // K/V projection: qkvT[e*198+j], rows 66..131 -> k, 132..197 -> v
  for (int idx = tid; idx < 132; idx += 512) {
    int half = idx / 66, d = idx % 66;
    int row = 66 + half * 66 + d;
    float acc[10];
    #pragma unroll
    for (int t = 0; t < 10; ++t) acc[t] = 0.f;
    for (int e = 0; e < 66; ++e) {
      float w = qkvT[e * 198 + row];
      const float* er = encD + e;
      #pragma unroll
      for (int t = 0; t < 10; ++t) acc[t] += w * er[t * 66];
    }
    float bias = qkv_b[row];
    float* dst = (half ? v_ws : k_ws) + (size_t)b * 660 + d;
    #pragma unroll
    for (int t = 0; t < 10; ++t) dst[t * 66] = acc[t] + bias;
  }
}

// ------------------------- prep: transposes + folds (all f32) ---------------

__global__ __launch_bounds__(512)
void prep_kernel(const float* __restrict__ qkv_w, const float* __restrict__ ow,
                 const float* __restrict__ ob, const float* __restrict__ lw,
                 const float* __restrict__ gru_wi, const float* __restrict__ gru_wh,
                 float* __restrict__ qkvT, float* __restrict__ wqD,
                 float* __restrict__ lwAT, float* __restrict__ MT,
                 float* __restrict__ cb2, float* __restrict__ wT_g)
{
  int idx = blockIdx.x * 512 + threadIdx.x;
  if (idx < 13068) {                 // qkvT[e*198+j] = qkv_w[j*66+e]
    int e = idx / 198, j = idx % 198;
    qkvT[idx] = qkv_w[j * 66 + e];
    return;
  }
  int i1 = idx - 13068;
  if (i1 < 4356) {                   // wqD[e*66+d] = qkv_w[d*66+e]
    int e = i1 / 66, d = i1 % 66;
    wqD[i1] = qkv_w[d * 66 + e];
    return;
  }
  int i2 = i1 - 4356;
  if (i2 < 4356) {                   // lwAT[e*66+d] = lw[d*132+e]
    int e = i2 / 66, d = i2 % 66;
    lwAT[i2] = lw[d * 132 + e];
    return;
  }
  int i3 = i2 - 4356;
  if (i3 < 4356) {                   // MT[e*66+d] = sum_f lwB[d][f]*ow[f][e]
    int e = i3 / 66, d = i3 % 66;
    const float* lrow = lw + d * 132 + 66;
    float acc = 0.f;
    for (int f = 0; f < 66; ++f) acc += lrow[f] * ow[f * 66 + e];
    MT[i3] = acc;
    return;
  }
  int i4 = i3 - 4356;
  if (i4 < 66) {                     // cb2[d] = lwB[d] @ ob
    const float* lrow = lw + i4 * 132 + 66;
    float acc = 0.f;
    for (int f = 0; f < 66; ++f) acc += lrow[f] * ob[f];
    cb2[i4] = acc;
    return;
  }
  int i5 = i4 - 66;
  if (i5 < 26136) {                  // wT_g[e*396+jm]: jm<198 wi, else wh
    int e = i5 / 396, jm = i5 % 396;
    wT_g[i5] = (jm < 198) ? gru_wi[jm * 66 + e] : gru_wh[(jm - 198) * 66 + e];
  }
}

// ---------------------------------------------------------------- decoder ---
// 512 blocks x 4 rows x 512 threads. GRU weights PERSISTENT IN REGISTERS
// (thread jm<396 holds its row's 66 weights; loaded once, coalesced).
// wq/lwA/M staged in LDS; k/v read from global (L1/L2-hot). ~65KB -> 2/CU.

__global__ __launch_bounds__(512, 4)
void dec_kernel(const float* __restrict__ x, const float* __restrict__ h0_ws,
                const float* __restrict__ k_ws, const float* __restrict__ v_ws,
                const float* __restrict__ wT_g,
                const float* __restrict__ gru_bi, const float* __restrict__ gru_bh,
                const float* __restrict__ wqD, const float* __restrict__ qkv_b,
                const float* __restrict__ lwAT, const float* __restrict__ MT,
                const float* __restrict__ cb2, const float* __restrict__ lb,
                float* __restrict__ outp)
{
  __shared__ __align__(16) float wqS[4356];      // 17424 B
  __shared__ __align__(16) float lwAS[4356];     // 17424 B
  __shared__ __align__(16) float MS[4356];       // 17424 B
  __shared__ __align__(16) float G[396 * 4];     //  6336 B
  __shared__ __align__(16) float tpT[264], hsT[264], qT[264], cxT[264];  // 4224 B
  __shared__ float attnS[120];                   //   480 B
  __shared__ float biS[198], bhS[198], bqS[66], lbS[66];  // 2112 B
  // total ~65.4 KB -> 2 blocks/CU

  const int tid = threadIdx.x;
  const int b0 = blockIdx.x * 4;

  // persistent GRU weights: thread jm holds w[e] = wT_g[e*396+jm]
  float wreg[66];
  if (tid < 396) {
    #pragma unroll
    for (int e = 0; e < 66; ++e) wreg[e] = wT_g[e * 396 + tid];
  }

  for (int idx = tid; idx < 4356; idx += 512) {
    wqS[idx] = wqD[idx]; lwAS[idx] = lwAT[idx]; MS[idx] = MT[idx];
  }
  for (int idx = tid; idx < 198; idx += 512) { biS[idx] = gru_bi[idx]; bhS[idx] = gru_bh[idx]; }
  for (int idx = tid; idx < 66; idx += 512)  { bqS[idx] = qkv_b[idx]; lbS[idx] = lb[idx] + cb2[idx]; }
  for (int idx = tid; idx < 264; idx += 512) {
    int d = idx >> 2, r = idx & 3;
    hsT[d * 4 + r] = h0_ws[(size_t)(b0 + r) * 66 + d];
    tpT[d * 4 + r] = x[(size_t)(b0 + r) * 660 + 594 + d];
  }
  __syncthreads();

  const float qscale = 1.0f / sqrtf(22.0f);

  for (int s = 0; s < 25; ++s) {
    // P1: G[jm] = act @ w_jm + bias (register weights, LDS-broadcast act)
    if (tid < 396) {
      const float* base = (tid < 198) ? tpT : hsT;
      float a0 = 0.f, a1 = 0.f, a2 = 0.f, a3 = 0.f;
      #pragma unroll
      for (int e = 0; e < 66; ++e) {
        float w = wreg[e];
        float4 av = *(const float4*)(base + e * 4);
        a0 += w * av.x; a1 += w * av.y; a2 += w * av.z; a3 += w * av.w;
      }
      float bias = (tid < 198) ? biS[tid] : bhS[tid - 198];
      *(float4*)(G + tid * 4) = make_float4(a0 + bias, a1 + bias, a2 + bias, a3 + bias);
    }
    __syncthreads();

    // P2: GRU gates -> hs
    if (tid < 264) {
      int d = tid >> 2, r = tid & 3;
      float ir = G[d * 4 + r]         + G[(198 + d) * 4 + r];
      float iz = G[(66 + d) * 4 + r]  + G[(264 + d) * 4 + r];
      float nx = G[(132 + d) * 4 + r];
      float hn = G[(330 + d) * 4 + r];
      float rg = 1.f / (1.f + __expf(-ir));
      float zg = 1.f / (1.f + __expf(-iz));
      float t2 = __expf(2.f * (nx + rg * hn));
      float ng = 1.f - 2.f / (t2 + 1.f);        // tanh, overflow-safe
      float h = hsT[d * 4 + r];
      hsT[d * 4 + r] = (1.f - zg) * ng + zg * h;
    }
    __syncthreads();

    // P3: q = (hs @ wq.T + bq)*scale
    if (tid < 264) {
      int r = tid / 66, d = tid % 66;
      float acc = 0.f;
      #pragma unroll 6
      for (int e = 0; e < 66; ++e)
        acc += wqS[e * 66 + d] * hsT[e * 4 + r];
      qT[d * 4 + r] = (acc + bqS[d]) * qscale;
    }
    __syncthreads();

    // P4: scores + softmax fused (12 (r,h) tasks; k from global, L1-hot)
    if (tid < 12) {
      int r = tid / 3, h = tid % 3;
      const float* kb = k_ws + (size_t)(b0 + r) * 660 + h * 22;
      float sc[10];
      float mx = -1e30f;
      #pragma unroll
      for (int t = 0; t < 10; ++t) {
        float acc = 0.f;
        const float* kp = kb + t * 66;
        #pragma unroll
        for (int dd = 0; dd < 22; ++dd)
          acc += qT[(h * 22 + dd) * 4 + r] * kp[dd];
        sc[t] = acc;
        mx = fmaxf(mx, acc);
      }
      float sum = 0.f;
      #pragma unroll
      for (int t = 0; t < 10; ++t) { float e = __expf(sc[t] - mx); sc[t] = e; sum += e; }
      float invs = 1.f / sum;
      #pragma unroll
      for (int t = 0; t < 10; ++t) attnS[tid * 10 + t] = sc[t] * invs;
    }
    __syncthreads();

    // P5: ctx_raw = attn @ v (v from global, L1/L2-hot)
    if (tid < 264) {
      int r = tid / 66, d = tid % 66, h = d / 22;
      const float* ap = attnS + (r * 3 + h) * 10;
      const float* vp = v_ws + (size_t)(b0 + r) * 660 + d;
      float acc = 0.f;
      #pragma unroll
      for (int t = 0; t < 10; ++t) acc += ap[t] * vp[t * 66];
      cxT[d * 4 + r] = acc;
    }
    __syncthreads();

    // P7: pred = lwA@hs + M@ctx_raw + (lb + lwB@ob) + tp
    if (tid < 264) {
      int r = tid / 66, d = tid % 66;
      float acc = 0.f;
      #pragma unroll 6
      for (int e = 0; e < 66; ++e)
        acc += lwAS[e * 66 + d] * hsT[e * 4 + r] + MS[e * 66 + d] * cxT[e * 4 + r];
      float pred = acc + lbS[d] + tpT[d * 4 + r];
      outp[((size_t)(b0 + r) * 25 + s) * 66 + d] = pred;
      tpT[d * 4 + r] = pred;
    }
    __syncthreads();
  }
}

// ----------------------------------------------------------------- launch ---

extern "C" void kernel_launch(void* const* d_in, const int* in_sizes, int n_in,
                              void* d_out, int out_size, void* d_ws, size_t ws_size,
                              hipStream_t stream) {
  (void)in_sizes; (void)n_in; (void)out_size; (void)ws_size;
  const float* x   = (const float*)d_in[0];
  const float* A   = (const float*)d_in[1];
  const float* Tm  = (const float*)d_in[2];
  const float* pre = (const float*)d_in[3];
  EncW W;
  for (int i = 0; i < 4; ++i) {
    W.cw[i]  = (const float*)d_in[4 + 8 * i + 0];
    W.cb[i]  = (const float*)d_in[4 + 8 * i + 1];
    W.g[i]   = (const float*)d_in[4 + 8 * i + 2];
    W.bt[i]  = (const float*)d_in[4 + 8 * i + 3];
    W.rw[i]  = (const float*)d_in[4 + 8 * i + 4];
    W.rb[i]  = (const float*)d_in[4 + 8 * i + 5];
    W.rg[i]  = (const float*)d_in[4 + 8 * i + 6];
    W.rbt[i] = (const float*)d_in[4 + 8 * i + 7];
  }
  const float* gru_wi = (const float*)d_in[36];
  const float* gru_wh = (const float*)d_in[37];
  const float* gru_bi = (const float*)d_in[38];
  const float* gru_bh = (const float*)d_in[39];
  const float* qkv_w  = (const float*)d_in[40];
  const float* qkv_b  = (const float*)d_in[41];
  const float* ow     = (const float*)d_in[42];
  const float* ob     = (const float*)d_in[43];
  const float* lw     = (const float*)d_in[44];
  const float* lb     = (const float*)d_in[45];

  float* wsf  = (float*)d_ws;
  float* h0   = wsf;                       // 2048*66
  float* kw   = h0 + 2048 * 66;            // 2048*660
  float* vw   = kw + 2048 * 660;           // 2048*660
  float* qkvT = vw + 2048 * 660;           // 13068
  float* wqD  = qkvT + 13068;              // 4356
  float* lwAT = wqD + 4356;                // 4356
  float* MT   = lwAT + 4356;               // 4356
  float* cb2  = MT + 4356;                 // 66
  float* wT_g = cb2 + 66;                  // 26136

  prep_kernel<<<103, 512, 0, stream>>>(qkv_w, ow, ob, lw, gru_wi, gru_wh,
                                       qkvT, wqD, lwAT, MT, cb2, wT_g);
  enc_kernel<<<2048, 512, 0, stream>>>(x, A, Tm, pre, W, qkvT, qkv_b, h0, kw, vw);
  dec_kernel<<<512, 512, 0, stream>>>(x, h0, kw, vw, wT_g, gru_bi, gru_bh,
                                      wqD, qkv_b, lwAT, MT, cb2, lb,
                                      (float*)d_out);
}

// Round 12
// 745.617 us; speedup vs baseline: 1.6422x; 1.6422x over previous
//
#include <hip/hip_runtime.h>

#define DEV static __device__ __forceinline__

// ---------------------------------------------------------------- encoder ---

struct EncW {
  const float* cw[4]; const float* cb[4]; const float* g[4]; const float* bt[4];
  const float* rw[4]; const float* rb[4]; const float* rg[4]; const float* rbt[4];
};

// One GCN layer, f32 activations, in-place in a 64x220 LDS buffer.
// act layout: [c][t*22+v], stride 220. S = 4840-float scratch multiplexed
// through rw -> Tm -> A -> cw (disjoint phases): LDS < 80KB, 2 blocks/CU.
template<int CI, int CO>
DEV void gcn_layer32(int tid,
    const float* __restrict__ cw, const float* __restrict__ cb,
    const float* __restrict__ gg, const float* __restrict__ bt,
    const float* __restrict__ rw, const float* __restrict__ rb,
    const float* __restrict__ rg, const float* __restrict__ rbt,
    const float* __restrict__ TmL, const float* __restrict__ AL, float preL,
    float* __restrict__ act, float* __restrict__ S,
    float* __restrict__ rmul, float* __restrict__ radd,
    float* __restrict__ cmul, float* __restrict__ cadd)
{
  constexpr int COP8 = (CO + 7) & ~7;         // 8, 32, or 64
  constexpr int NT = (COP8 / 8) * 55;         // o-oct x p-quad tasks (<=440)
  const float inv = 0.99999499987f;           // 1/sqrt(1+1e-5)

  // ---- stage rw^T (padded) + BN consts ----
  for (int idx = tid; idx < CI * COP8; idx += 512) {
    int c = idx / COP8, o = idx % COP8;
    S[idx] = (o < CO) ? rw[o * CI + c] : 0.f;
  }
  for (int idx = tid; idx < 64; idx += 512) {
    bool ok = idx < CO;
    float rm = ok ? rg[idx] * inv : 0.f;
    float cm = ok ? gg[idx] * inv : 0.f;
    rmul[idx] = rm;
    radd[idx] = ok ? rb[idx] * rm + rbt[idx] : 0.f;
    cmul[idx] = cm;
    cadd[idx] = ok ? cb[idx] * cm + bt[idx] : 0.f;
  }
  __syncthreads();

  // ---- 2a: residual channel-mix -> registers (BN applied) ----
  float racc[32];
  int oo = tid / 55, pp = tid % 55;     // valid when tid < NT
  if (tid < NT) {
    #pragma unroll
    for (int k = 0; k < 32; ++k) racc[k] = 0.f;
    #pragma unroll 4
    for (int c = 0; c < CI; ++c) {
      const float* wr = S + c * COP8 + oo * 8;
      float4 w0 = *(const float4*)(wr);
      float4 w1 = *(const float4*)(wr + 4);
      float4 av = *(const float4*)(act + c * 220 + pp * 4);
      float wv[8] = {w0.x,w0.y,w0.z,w0.w,w1.x,w1.y,w1.z,w1.w};
      #pragma unroll
      for (int o = 0; o < 8; ++o) {
        racc[o*4+0] += wv[o]*av.x; racc[o*4+1] += wv[o]*av.y;
        racc[o*4+2] += wv[o]*av.z; racc[o*4+3] += wv[o]*av.w;
      }
    }
    #pragma unroll
    for (int o = 0; o < 8; ++o) {
      float m = rmul[oo * 8 + o], a = radd[oo * 8 + o];
      #pragma unroll
      for (int k = 0; k < 4; ++k) racc[o*4+k] = racc[o*4+k]*m + a;
    }
  }
  __syncthreads();

  // ---- stage TmT: S[(t*10+q)*22+v] = Tm[v*100+t*10+q] ----
  for (int idx = tid; idx < 2200; idx += 512) {
    int tq = idx / 22, v = idx % 22;
    int t = tq / 10, q = tq % 10;
    S[idx] = TmL[v * 100 + t * 10 + q];
  }
  __syncthreads();

  // ---- 2b: temporal mix, in place (v2-major) ----
  for (int idx = tid; idx < CI * 11; idx += 512) {
    int v2 = idx % 11, c = idx / 11;
    float* base = act + c * 220 + v2 * 2;
    float xin[10][2];
    #pragma unroll
    for (int t = 0; t < 10; ++t) { xin[t][0] = base[t*22]; xin[t][1] = base[t*22+1]; }
    float ya[10][2];
    #pragma unroll
    for (int q = 0; q < 10; ++q) { ya[q][0] = 0.f; ya[q][1] = 0.f; }
    #pragma unroll
    for (int t = 0; t < 10; ++t) {
      const float* tm = S + t * 220 + v2 * 2;
      #pragma unroll
      for (int q = 0; q < 10; ++q) {
        ya[q][0] += tm[q*22]   * xin[t][0];
        ya[q][1] += tm[q*22+1] * xin[t][1];
      }
    }
    #pragma unroll
    for (int q = 0; q < 10; ++q) { base[q*22] = ya[q][0]; base[q*22+1] = ya[q][1]; }
  }
  __syncthreads();

  // ---- stage A ----
  for (int idx = tid; idx < 4840; idx += 512) S[idx] = AL[idx];
  __syncthreads();

  // ---- 3: spatial mix, in place (t-major) ----
  for (int idx = tid; idx < CI * 10; idx += 512) {
    int t = idx % 10, c = idx / 10;
    float* row = act + c * 220 + t * 22;
    float yin[22];
    #pragma unroll
    for (int v = 0; v < 22; ++v) yin[v] = row[v];
    float za[22];
    #pragma unroll
    for (int w = 0; w < 22; ++w) za[w] = 0.f;
    #pragma unroll 2
    for (int v = 0; v < 22; ++v) {
      const float* ar = S + (t * 22 + v) * 22;
      float y0 = yin[v];
      #pragma unroll
      for (int w = 0; w < 22; ++w) za[w] += y0 * ar[w];
    }
    #pragma unroll
    for (int w = 0; w < 22; ++w) row[w] = za[w];
  }
  __syncthreads();

  // ---- stage cw^T ----
  for (int idx = tid; idx < CI * COP8; idx += 512) {
    int c = idx / COP8, o = idx % COP8;
    S[idx] = (o < CO) ? cw[o * CI + c] : 0.f;
  }
  __syncthreads();

  // ---- 4: main channel-mix into registers, barrier, in-place write ----
  float cacc[32];
  if (tid < NT) {
    #pragma unroll
    for (int k = 0; k < 32; ++k) cacc[k] = 0.f;
    #pragma unroll 4
    for (int c = 0; c < CI; ++c) {
      const float* wr = S + c * COP8 + oo * 8;
      float4 w0 = *(const float4*)(wr);
      float4 w1 = *(const float4*)(wr + 4);
      float4 av = *(const float4*)(act + c * 220 + pp * 4);
      float wv[8] = {w0.x,w0.y,w0.z,w0.w,w1.x,w1.y,w1.z,w1.w};
      #pragma unroll
      for (int o = 0; o < 8; ++o) {
        cacc[o*4+0] += wv[o]*av.x; cacc[o*4+1] += wv[o]*av.y;
        cacc[o*4+2] += wv[o]*av.z; cacc[o*4+3] += wv[o]*av.w;
      }
    }
  }
  __syncthreads();   // all reads of act complete before overwrite
  if (tid < NT) {
    #pragma unroll
    for (int o = 0; o < 8; ++o) {
      float m = cmul[oo * 8 + o], a = cadd[oo * 8 + o];
      #pragma unroll
      for (int k = 0; k < 4; ++k) {
        float y = cacc[o*4+k]*m + a + racc[o*4+k];
        act[(oo*8+o)*220 + pp*4 + k] = (y >= 0.f) ? y : preL * y;
      }
    }
  }
  __syncthreads();
}

__global__ __launch_bounds__(512, 4)
void enc_kernel(const float* __restrict__ x, const float* __restrict__ A,
                const float* __restrict__ Tm, const float* __restrict__ pre, EncW W,
                const float* __restrict__ qkvT, const float* __restrict__ qkv_b,
                float* __restrict__ h0_ws, float* __restrict__ k_ws,
                float* __restrict__ v_ws)
{
  __shared__ __align__(16) float act[64 * 220];   // 56320 B
  __shared__ __align__(16) float S[4840];         // 19360 B (rw/Tm/A/cw mux)
  __shared__ float rmul[64], radd[64], cmul[64], cadd[64];  // 1024 B

  const int tid = threadIdx.x;
  const int b = blockIdx.x;

  for (int idx = tid; idx < 660; idx += 512) {
    int c = idx / 220, r = idx % 220, t = r / 22, v = r % 22;
    act[c * 220 + t * 22 + v] = x[(((size_t)b * 10 + t) * 22 + v) * 3 + c];
  }
  float p0 = pre[0], p1 = pre[1], p2 = pre[2], p3 = pre[3];

  gcn_layer32<3, 64>(tid, W.cw[0], W.cb[0], W.g[0], W.bt[0], W.rw[0], W.rb[0], W.rg[0], W.rbt[0],
                     Tm, A, p0, act, S, rmul, radd, cmul, cadd);
  gcn_layer32<64, 32>(tid, W.cw[1], W.cb[1], W.g[1], W.bt[1], W.rw[1], W.rb[1], W.rg[1], W.rbt[1],
                     Tm + 2200, A + 4840, p1, act, S, rmul, radd, cmul, cadd);
  gcn_layer32<32, 64>(tid, W.cw[2], W.cb[2], W.g[2], W.bt[2], W.rw[2], W.rb[2], W.rg[2], W.rbt[2],
                     Tm + 4400, A + 9680, p2, act, S, rmul, radd, cmul, cadd);
  gcn_layer32<64, 3>(tid, W.cw[3], W.cb[3], W.g[3], W.bt[3], W.rw[3], W.rb[3], W.rg[3], W.rbt[3],
                     Tm + 6600, A + 14520, p3, act, S, rmul, radd, cmul, cadd);

  // build encD[t][d=v*3+c] in act rows 3..5; store h0
  float* encD = act + 3 * 220;
  for (int idx = tid; idx < 660; idx += 512) {
    int t = idx / 66, d = idx % 66, v = d / 3, c = d % 3;
    float val = act[c * 220 + t * 22 + v];
    encD[idx] = val;
    if (t == 9) h0_ws[(size_t)b * 66 + d] = val;
  }
  __syncthreads();

  // K/V projection: qkvT[e*198+j], rows 66..131 -> k, 132..197 -> v
  for (int idx = tid; idx < 132; idx += 512) {
    int half = idx / 66, d = idx % 66;
    int row = 66 + half * 66 + d;
    float acc[10];
    #pragma unroll
    for (int t = 0; t < 10; ++t) acc[t] = 0.f;
    for (int e = 0; e < 66; ++e) {
      float w = qkvT[e * 198 + row];
      const float* er = encD + e;
      #pragma unroll
      for (int t = 0; t < 10; ++t) acc[t] += w * er[t * 66];
    }
    float bias = qkv_b[row];
    float* dst = (half ? v_ws : k_ws) + (size_t)b * 660 + d;
    #pragma unroll
    for (int t = 0; t < 10; ++t) dst[t * 66] = acc[t] + bias;
  }
}

// ------------------------- prep: transposes + folds (all f32) ---------------

__global__ __launch_bounds__(512)
void prep_kernel(const float* __restrict__ qkv_w, const float* __restrict__ ow,
                 const float* __restrict__ ob, const float* __restrict__ lw,
                 const float* __restrict__ gru_wi, const float* __restrict__ gru_wh,
                 float* __restrict__ qkvT, float* __restrict__ wqD,
                 float* __restrict__ lwAT, float* __restrict__ MT,
                 float* __restrict__ cb2, float* __restrict__ wT_g)
{
  int idx = blockIdx.x * 512 + threadIdx.x;
  if (idx < 13068) {                 // qkvT[e*198+j] = qkv_w[j*66+e]
    int e = idx / 198, j = idx % 198;
    qkvT[idx] = qkv_w[j * 66 + e];
    return;
  }
  int i1 = idx - 13068;
  if (i1 < 4356) {                   // wqD[e*66+d] = qkv_w[d*66+e]
    int e = i1 / 66, d = i1 % 66;
    wqD[i1] = qkv_w[d * 66 + e];
    return;
  }
  int i2 = i1 - 4356;
  if (i2 < 4356) {                   // lwAT[e*66+d] = lw[d*132+e]
    int e = i2 / 66, d = i2 % 66;
    lwAT[i2] = lw[d * 132 + e];
    return;
  }
  int i3 = i2 - 4356;
  if (i3 < 4356) {                   // MT[e*66+d] = sum_f lwB[d][f]*ow[f][e]
    int e = i3 / 66, d = i3 % 66;
    const float* lrow = lw + d * 132 + 66;
    float acc = 0.f;
    for (int f = 0; f < 66; ++f) acc += lrow[f] * ow[f * 66 + e];
    MT[i3] = acc;
    return;
  }
  int i4 = i3 - 4356;
  if (i4 < 66) {                     // cb2[d] = lwB[d] @ ob
    const float* lrow = lw + i4 * 132 + 66;
    float acc = 0.f;
    for (int f = 0; f < 66; ++f) acc += lrow[f] * ob[f];
    cb2[i4] = acc;
    return;
  }
  int i5 = i4 - 66;
  if (i5 < 26136) {                  // wT_g[e*396+jm]: jm<198 wi, else wh
    int e = i5 / 396, jm = i5 % 396;
    wT_g[i5] = (jm < 198) ? gru_wi[jm * 66 + e] : gru_wh[(jm - 198) * 66 + e];
  }
}

// ---------------------------------------------------------------- decoder ---
// 512 blocks x 4 rows x 512 threads. wi/wh streamed per step from L2 (wT_g,
// coalesced, L2-resident); wq/lwA/M + k staged in LDS. ~76KB -> 2 blocks/CU.
// (The R11 register-weight scheme spilled to scratch: 1 GB HBM traffic. Do
//  NOT hold 66-float arrays per thread under a waves-per-EU launch bound.)

__global__ __launch_bounds__(512, 4)
void dec_kernel(const float* __restrict__ x, const float* __restrict__ h0_ws,
                const float* __restrict__ k_ws, const float* __restrict__ v_ws,
                const float* __restrict__ wT_g,
                const float* __restrict__ gru_bi, const float* __restrict__ gru_bh,
                const float* __restrict__ wqD, const float* __restrict__ qkv_b,
                const float* __restrict__ lwAT, const float* __restrict__ MT,
                const float* __restrict__ cb2, const float* __restrict__ lb,
                float* __restrict__ outp)
{
  __shared__ __align__(16) float wqS[4356];      // 17424 B
  __shared__ __align__(16) float lwAS[4356];     // 17424 B
  __shared__ __align__(16) float MS[4356];       // 17424 B
  __shared__ __align__(16) float kS[2640];       // 10560 B
  __shared__ __align__(16) float G[396 * 4];     //  6336 B
  __shared__ __align__(16) float tpT[264], hsT[264], qT[264], cxT[264];  // 4224 B
  __shared__ float attnS[120];                   //   480 B
  __shared__ float biS[198], bhS[198], bqS[66], lbS[66];  // 2112 B
  // total ~75.9 KB -> 2 blocks/CU

  const int tid = threadIdx.x;
  const int b0 = blockIdx.x * 4;

  for (int idx = tid; idx < 4356; idx += 512) {
    wqS[idx] = wqD[idx]; lwAS[idx] = lwAT[idx]; MS[idx] = MT[idx];
  }
  for (int idx = tid; idx < 2640; idx += 512) {
    int r = idx / 660, rest = idx % 660;
    kS[idx] = k_ws[(size_t)(b0 + r) * 660 + rest];
  }
  for (int idx = tid; idx < 198; idx += 512) { biS[idx] = gru_bi[idx]; bhS[idx] = gru_bh[idx]; }
  for (int idx = tid; idx < 66; idx += 512)  { bqS[idx] = qkv_b[idx]; lbS[idx] = lb[idx] + cb2[idx]; }
  for (int idx = tid; idx < 264; idx += 512) {
    int d = idx >> 2, r = idx & 3;
    hsT[d * 4 + r] = h0_ws[(size_t)(b0 + r) * 66 + d];
    tpT[d * 4 + r] = x[(size_t)(b0 + r) * 660 + 594 + d];
  }
  __syncthreads();

  const float qscale = 1.0f / sqrtf(22.0f);

  for (int s = 0; s < 25; ++s) {
    // P1: G[jm] = act @ w_jm + bias (weights streamed from L2, coalesced)
    if (tid < 396) {
      const float* base = (tid < 198) ? tpT : hsT;
      const float* wp = wT_g + tid;
      float a0 = 0.f, a1 = 0.f, a2 = 0.f, a3 = 0.f;
      #pragma unroll 11
      for (int e = 0; e < 66; ++e) {
        float w = wp[e * 396];
        float4 av = *(const float4*)(base + e * 4);
        a0 += w * av.x; a1 += w * av.y; a2 += w * av.z; a3 += w * av.w;
      }
      float bias = (tid < 198) ? biS[tid] : bhS[tid - 198];
      *(float4*)(G + tid * 4) = make_float4(a0 + bias, a1 + bias, a2 + bias, a3 + bias);
    }
    __syncthreads();

    // P2: GRU gates -> hs
    if (tid < 264) {
      int d = tid >> 2, r = tid & 3;
      float ir = G[d * 4 + r]         + G[(198 + d) * 4 + r];
      float iz = G[(66 + d) * 4 + r]  + G[(264 + d) * 4 + r];
      float nx = G[(132 + d) * 4 + r];
      float hn = G[(330 + d) * 4 + r];
      float rg = 1.f / (1.f + __expf(-ir));
      float zg = 1.f / (1.f + __expf(-iz));
      float t2 = __expf(2.f * (nx + rg * hn));
      float ng = 1.f - 2.f / (t2 + 1.f);        // tanh, overflow-safe
      float h = hsT[d * 4 + r];
      hsT[d * 4 + r] = (1.f - zg) * ng + zg * h;
    }
    __syncthreads();

    // P3: q = (hs @ wq.T + bq)*scale
    if (tid < 264) {
      int r = tid / 66, d = tid % 66;
      float acc = 0.f;
      #pragma unroll 6
      for (int e = 0; e < 66; ++e)
        acc += wqS[e * 66 + d] * hsT[e * 4 + r];
      qT[d * 4 + r] = (acc + bqS[d]) * qscale;
    }
    __syncthreads();

    // P4a: scores (120 tasks: r,h,t; k in LDS)
    if (tid < 120) {
      int r = tid / 30, rem = tid % 30, h = rem / 10, t = rem % 10;
      const float* kp = kS + r * 660 + t * 66 + h * 22;
      const float* qp = qT + (h * 22) * 4 + r;
      float acc = 0.f;
      #pragma unroll
      for (int dd = 0; dd < 22; ++dd) acc += qp[dd * 4] * kp[dd];
      attnS[(r * 3 + h) * 10 + t] = acc;
    }
    __syncthreads();

    // P4b: softmax (12 tasks)
    if (tid < 12) {
      float* sp = attnS + tid * 10;
      float mx = sp[0];
      #pragma unroll
      for (int t = 1; t < 10; ++t) mx = fmaxf(mx, sp[t]);
      float sum = 0.f;
      #pragma unroll
      for (int t = 0; t < 10; ++t) { float e = __expf(sp[t] - mx); sp[t] = e; sum += e; }
      float invs = 1.f / sum;
      #pragma unroll
      for (int t = 0; t < 10; ++t) sp[t] *= invs;
    }
    __syncthreads();

    // P5: ctx_raw = attn @ v (v from global, d-coalesced, L1/L2-hot)
    if (tid < 264) {
      int r = tid / 66, d = tid % 66, h = d / 22;
      const float* ap = attnS + (r * 3 + h) * 10;
      const float* vp = v_ws + (size_t)(b0 + r) * 660 + d;
      float acc = 0.f;
      #pragma unroll
      for (int t = 0; t < 10; ++t) acc += ap[t] * vp[t * 66];
      cxT[d * 4 + r] = acc;
    }
    __syncthreads();

    // P7: pred = lwA@hs + M@ctx_raw + (lb + lwB@ob) + tp
    if (tid < 264) {
      int r = tid / 66, d = tid % 66;
      float acc = 0.f;
      #pragma unroll 6
      for (int e = 0; e < 66; ++e)
        acc += lwAS[e * 66 + d] * hsT[e * 4 + r] + MS[e * 66 + d] * cxT[e * 4 + r];
      float pred = acc + lbS[d] + tpT[d * 4 + r];
      outp[((size_t)(b0 + r) * 25 + s) * 66 + d] = pred;
      tpT[d * 4 + r] = pred;
    }
    __syncthreads();
  }
}

// ----------------------------------------------------------------- launch ---

extern "C" void kernel_launch(void* const* d_in, const int* in_sizes, int n_in,
                              void* d_out, int out_size, void* d_ws, size_t ws_size,
                              hipStream_t stream) {
  (void)in_sizes; (void)n_in; (void)out_size; (void)ws_size;
  const float* x   = (const float*)d_in[0];
  const float* A   = (const float*)d_in[1];
  const float* Tm  = (const float*)d_in[2];
  const float* pre = (const float*)d_in[3];
  EncW W;
  for (int i = 0; i < 4; ++i) {
    W.cw[i]  = (const float*)d_in[4 + 8 * i + 0];
    W.cb[i]  = (const float*)d_in[4 + 8 * i + 1];
    W.g[i]   = (const float*)d_in[4 + 8 * i + 2];
    W.bt[i]  = (const float*)d_in[4 + 8 * i + 3];
    W.rw[i]  = (const float*)d_in[4 + 8 * i + 4];
    W.rb[i]  = (const float*)d_in[4 + 8 * i + 5];
    W.rg[i]  = (const float*)d_in[4 + 8 * i + 6];
    W.rbt[i] = (const float*)d_in[4 + 8 * i + 7];
  }
  const float* gru_wi = (const float*)d_in[36];
  const float* gru_wh = (const float*)d_in[37];
  const float* gru_bi = (const float*)d_in[38];
  const float* gru_bh = (const float*)d_in[39];
  const float* qkv_w  = (const float*)d_in[40];
  const float* qkv_b  = (const float*)d_in[41];
  const float* ow     = (const float*)d_in[42];
  const float* ob     = (const float*)d_in[43];
  const float* lw     = (const float*)d_in[44];
  const float* lb     = (const float*)d_in[45];

  float* wsf  = (float*)d_ws;
  float* h0   = wsf;                       // 2048*66
  float* kw   = h0 + 2048 * 66;            // 2048*660
  float* vw   = kw + 2048 * 660;           // 2048*660
  float* qkvT = vw + 2048 * 660;           // 13068
  float* wqD  = qkvT + 13068;              // 4356
  float* lwAT = wqD + 4356;                // 4356
  float* MT   = lwAT + 4356;               // 4356
  float* cb2  = MT + 4356;                 // 66
  float* wT_g = cb2 + 66;                  // 26136

  prep_kernel<<<103, 512, 0, stream>>>(qkv_w, ow, ob, lw, gru_wi, gru_wh,
                                       qkvT, wqD, lwAT, MT, cb2, wT_g);
  enc_kernel<<<2048, 512, 0, stream>>>(x, A, Tm, pre, W, qkvT, qkv_b, h0, kw, vw);
  dec_kernel<<<512, 512, 0, stream>>>(x, h0, kw, vw, wT_g, gru_bi, gru_bh,
                                      wqD, qkv_b, lwAT, MT, cb2, lb,
                                      (float*)d_out);
}